// Round 1
// 271.179 us; speedup vs baseline: 1.0044x; 1.0044x over previous
//
#include <hip/hip_runtime.h>
#include <math.h>

#define BATCH   32768
#define NCLS    1000
#define NC4     250      // 1000/4 float4 chunks per row
#define NBLOCKS 2048
#define NWAVES  (NBLOCKS * 4)   // 8192 waves
#define RPW     (BATCH / NWAVES) // 4 rows per wave (strided by NWAVES)

// One transcendental per element: flip sign of x by target predicate, then
// a single __expf feeds either sn (t==0) or sp (t!=0).
__device__ __forceinline__ void acc4(float4 xv, int4 tv, float& sn, float& sp) {
    float e0 = __expf(tv.x == 0 ? xv.x : -xv.x);
    float e1 = __expf(tv.y == 0 ? xv.y : -xv.y);
    float e2 = __expf(tv.z == 0 ? xv.z : -xv.z);
    float e3 = __expf(tv.w == 0 ? xv.w : -xv.w);
    sn += (tv.x == 0) ? e0 : 0.0f;  sp += (tv.x == 0) ? 0.0f : e0;
    sn += (tv.y == 0) ? e1 : 0.0f;  sp += (tv.y == 0) ? 0.0f : e1;
    sn += (tv.z == 0) ? e2 : 0.0f;  sp += (tv.z == 0) ? 0.0f : e2;
    sn += (tv.w == 0) ? e3 : 0.0f;  sp += (tv.w == 0) ? 0.0f : e3;
}

// Wave-per-row persistent kernel, software-pipelined one row deep:
// while chunk j of row r is consumed, chunk j of row r+1 is already being
// loaded into the freed register slot. The wave keeps ~8 dwordx4 loads in
// flight through the exp math AND the shuffle reduction, instead of the
// previous load->vmcnt(0)->use serialization (VGPR_Count=32 proved the
// intended staging never materialized).
__global__ __launch_bounds__(256) void lsep_row_kernel(
    const float* __restrict__ x,
    const int*   __restrict__ t,
    float* __restrict__ wave_out) {

    const int tid   = threadIdx.x;
    const int lane  = tid & 63;
    const int gwave = blockIdx.x * 4 + (tid >> 6);   // 0..NWAVES-1

    const bool tail = (lane + 192 < NC4);            // lanes 0..57 own chunk 3

    const float4* xp = (const float4*)x + (size_t)gwave * NC4;
    const int4*   tp = (const int4*)t + (size_t)gwave * NC4;
    const size_t rstep = (size_t)NWAVES * NC4;       // float4 stride, +NWAVES rows

    float4 xv0, xv1, xv2, xv3;
    int4   tv0, tv1, tv2, tv3;

    // prologue: stage row 0 (8 independent loads)
    xv0 = xp[lane];       tv0 = tp[lane];
    xv1 = xp[lane + 64];  tv1 = tp[lane + 64];
    xv2 = xp[lane + 128]; tv2 = tp[lane + 128];
    if (tail) { xv3 = xp[lane + 192]; tv3 = tp[lane + 192]; }

    float acc = 0.0f;   // lane 0: running sum of sn*sp over this wave's rows

    #pragma unroll
    for (int r = 0; r < RPW; ++r) {
        const bool more = (r + 1 < RPW);             // compile-time after unroll
        const float4* xn = xp + (size_t)(r + 1) * rstep;
        const int4*   tn = tp + (size_t)(r + 1) * rstep;

        float sn = 0.0f, sp = 0.0f;

        {   // chunk 0: free the slot, issue next-row load, then compute
            float4 xc = xv0; int4 tc = tv0;
            if (more) { xv0 = xn[lane]; tv0 = tn[lane]; }
            acc4(xc, tc, sn, sp);
        }
        {   // chunk 1
            float4 xc = xv1; int4 tc = tv1;
            if (more) { xv1 = xn[lane + 64]; tv1 = tn[lane + 64]; }
            acc4(xc, tc, sn, sp);
        }
        {   // chunk 2
            float4 xc = xv2; int4 tc = tv2;
            if (more) { xv2 = xn[lane + 128]; tv2 = tn[lane + 128]; }
            acc4(xc, tc, sn, sp);
        }
        if (tail) {   // chunk 3 (partial: 250 = 3*64 + 58)
            float4 xc = xv3; int4 tc = tv3;
            if (more) { xv3 = xn[lane + 192]; tv3 = tn[lane + 192]; }
            acc4(xc, tc, sn, sp);
        }

        // 64-lane shuffle reduction; next row's 8 loads are in flight under it
        #pragma unroll
        for (int off = 32; off > 0; off >>= 1) {
            sn += __shfl_down(sn, off, 64);
            sp += __shfl_down(sp, off, 64);
        }

        if (lane == 0) acc += sn * sp;
    }

    if (lane == 0) wave_out[gwave] = acc;
}

// Single block reduces NWAVES partials: 8 independent float4 loads per
// thread (fully unrolled), shuffle + LDS reduce, log1p.
__global__ __launch_bounds__(256) void lsep_reduce_kernel(
    const float* __restrict__ wave_out,
    float* __restrict__ out) {

    const int tid = threadIdx.x;
    const float4* r4 = (const float4*)wave_out;   // NWAVES/4 = 2048 float4

    float4 a[8];
    #pragma unroll
    for (int j = 0; j < 8; ++j)
        a[j] = r4[tid + 256 * j];

    float v = 0.0f;
    #pragma unroll
    for (int j = 0; j < 8; ++j)
        v += (a[j].x + a[j].y) + (a[j].z + a[j].w);

    #pragma unroll
    for (int off = 32; off > 0; off >>= 1)
        v += __shfl_down(v, off, 64);

    __shared__ float sv[4];
    const int wave = tid >> 6;
    const int lane = tid & 63;
    if (lane == 0) sv[wave] = v;
    __syncthreads();

    if (tid == 0) {
        float total = (sv[0] + sv[1]) + (sv[2] + sv[3]);
        out[0] = log1pf(total);
    }
}

extern "C" void kernel_launch(void* const* d_in, const int* in_sizes, int n_in,
                              void* d_out, int out_size, void* d_ws, size_t ws_size,
                              hipStream_t stream) {
    const float* x = (const float*)d_in[0];
    const int*   t = (const int*)d_in[1];
    float* out     = (float*)d_out;
    float* wave_ws = (float*)d_ws;   // NWAVES floats = 32 KB

    lsep_row_kernel<<<NBLOCKS, 256, 0, stream>>>(x, t, wave_ws);
    lsep_reduce_kernel<<<1, 256, 0, stream>>>(wave_ws, out);
}

// Round 2
// 269.863 us; speedup vs baseline: 1.0093x; 1.0049x over previous
//
#include <hip/hip_runtime.h>
#include <math.h>

#define BATCH   32768
#define NCLS    1000
#define NC4     250      // 1000/4 float4 chunks per row
#define NBLOCKS 2048
#define NWAVES  (NBLOCKS * 4)   // 8192 waves
#define RPW     (BATCH / NWAVES) // 4 rows per wave (strided by NWAVES)

// One transcendental per element: flip sign by target predicate, single
// __expf feeds either sn (t==0) or sp (t!=0).
__device__ __forceinline__ void acc4(float4 xv, int4 tv, float& sn, float& sp) {
    float e0 = __expf(tv.x == 0 ? xv.x : -xv.x);
    float e1 = __expf(tv.y == 0 ? xv.y : -xv.y);
    float e2 = __expf(tv.z == 0 ? xv.z : -xv.z);
    float e3 = __expf(tv.w == 0 ? xv.w : -xv.w);
    sn += (tv.x == 0) ? e0 : 0.0f;  sp += (tv.x == 0) ? 0.0f : e0;
    sn += (tv.y == 0) ? e1 : 0.0f;  sp += (tv.y == 0) ? 0.0f : e1;
    sn += (tv.z == 0) ? e2 : 0.0f;  sp += (tv.z == 0) ? 0.0f : e2;
    sn += (tv.w == 0) ? e3 : 0.0f;  sp += (tv.w == 0) ? 0.0f : e3;
}

// Wave-per-row persistent kernel, TWO rows interleaved per iteration.
// __launch_bounds__(256, 4): explicitly target 4 waves/EU (16 waves/CU),
// raising the VGPR cap to 128 so the allocator can keep all 16 of a row
// pair's dwordx4 loads staged in registers. Rounds 0-1 proved that at the
// default occupancy target the allocator collapses any source-level
// pipeline to ~1 load in flight (VGPR_Count 32/40, dur identical).
// Interleaving rows A and B means all 16 loads are live across both
// rows' accumulation, a dependency structure the scheduler cannot sink.
__global__ __launch_bounds__(256, 4) void lsep_row_kernel(
    const float* __restrict__ x,
    const int*   __restrict__ t,
    float* __restrict__ wave_out) {

    const int tid   = threadIdx.x;
    const int lane  = tid & 63;
    const int gwave = blockIdx.x * 4 + (tid >> 6);   // 0..NWAVES-1

    const bool tail = (lane + 192 < NC4);            // lanes 0..57 own chunk 3

    const float4* xp = (const float4*)x + (size_t)gwave * NC4;
    const int4*   tp = (const int4*)t + (size_t)gwave * NC4;
    const size_t rstep = (size_t)NWAVES * NC4;       // float4 stride, +NWAVES rows

    float acc = 0.0f;   // lane 0: running sum of sn*sp over this wave's rows

    #pragma unroll
    for (int pr = 0; pr < RPW / 2; ++pr) {
        const float4* xA = xp + (size_t)(2 * pr)     * rstep;
        const int4*   tA = tp + (size_t)(2 * pr)     * rstep;
        const float4* xB = xp + (size_t)(2 * pr + 1) * rstep;
        const int4*   tB = tp + (size_t)(2 * pr + 1) * rstep;

        // ---- issue all 16 loads for the row pair (64 data VGPRs) ----
        float4 xa0, xa1, xa2, xa3, xb0, xb1, xb2, xb3;
        int4   ta0, ta1, ta2, ta3, tb0, tb1, tb2, tb3;

        xa0 = xA[lane];       ta0 = tA[lane];
        xb0 = xB[lane];       tb0 = tB[lane];
        xa1 = xA[lane + 64];  ta1 = tA[lane + 64];
        xb1 = xB[lane + 64];  tb1 = tB[lane + 64];
        xa2 = xA[lane + 128]; ta2 = tA[lane + 128];
        xb2 = xB[lane + 128]; tb2 = tB[lane + 128];
        if (tail) {
            xa3 = xA[lane + 192]; ta3 = tA[lane + 192];
            xb3 = xB[lane + 192]; tb3 = tB[lane + 192];
        }

        // ---- interleaved consumption: A and B alternate, so every load
        //      stays live until deep into the pair's compute ----
        float snA = 0.0f, spA = 0.0f, snB = 0.0f, spB = 0.0f;
        acc4(xa0, ta0, snA, spA);
        acc4(xb0, tb0, snB, spB);
        acc4(xa1, ta1, snA, spA);
        acc4(xb1, tb1, snB, spB);
        acc4(xa2, ta2, snA, spA);
        acc4(xb2, tb2, snB, spB);
        if (tail) {
            acc4(xa3, ta3, snA, spA);
            acc4(xb3, tb3, snB, spB);
        }

        // ---- four independent 64-lane shuffle reductions ----
        #pragma unroll
        for (int off = 32; off > 0; off >>= 1) {
            snA += __shfl_down(snA, off, 64);
            spA += __shfl_down(spA, off, 64);
            snB += __shfl_down(snB, off, 64);
            spB += __shfl_down(spB, off, 64);
        }

        if (lane == 0) acc += snA * spA + snB * spB;
    }

    if (lane == 0) wave_out[gwave] = acc;
}

// Single block reduces NWAVES partials: 8 independent float4 loads per
// thread (fully unrolled), shuffle + LDS reduce, log1p.
__global__ __launch_bounds__(256) void lsep_reduce_kernel(
    const float* __restrict__ wave_out,
    float* __restrict__ out) {

    const int tid = threadIdx.x;
    const float4* r4 = (const float4*)wave_out;   // NWAVES/4 = 2048 float4

    float4 a[8];
    #pragma unroll
    for (int j = 0; j < 8; ++j)
        a[j] = r4[tid + 256 * j];

    float v = 0.0f;
    #pragma unroll
    for (int j = 0; j < 8; ++j)
        v += (a[j].x + a[j].y) + (a[j].z + a[j].w);

    #pragma unroll
    for (int off = 32; off > 0; off >>= 1)
        v += __shfl_down(v, off, 64);

    __shared__ float sv[4];
    const int wave = tid >> 6;
    const int lane = tid & 63;
    if (lane == 0) sv[wave] = v;
    __syncthreads();

    if (tid == 0) {
        float total = (sv[0] + sv[1]) + (sv[2] + sv[3]);
        out[0] = log1pf(total);
    }
}

extern "C" void kernel_launch(void* const* d_in, const int* in_sizes, int n_in,
                              void* d_out, int out_size, void* d_ws, size_t ws_size,
                              hipStream_t stream) {
    const float* x = (const float*)d_in[0];
    const int*   t = (const int*)d_in[1];
    float* out     = (float*)d_out;
    float* wave_ws = (float*)d_ws;   // NWAVES floats = 32 KB

    lsep_row_kernel<<<NBLOCKS, 256, 0, stream>>>(x, t, wave_ws);
    lsep_reduce_kernel<<<1, 256, 0, stream>>>(wave_ws, out);
}